// Round 7
// baseline (391.705 us; speedup 1.0000x reference)
//
#include <hip/hip_runtime.h>
#include <stdint.h>

#define NN 50000
#define NE 800000
#define FD 64
#define HD 128

typedef __attribute__((ext_vector_type(8))) short short8;   // 8 bf16 (4 VGPRs)
typedef __attribute__((ext_vector_type(4))) float f32x4;    // MFMA acc

// ---------- bf16 helpers ----------
__device__ __forceinline__ float bflo(unsigned int v) {
    union { unsigned int u; float f; } c; c.u = v << 16; return c.f;
}
__device__ __forceinline__ float bfhi(unsigned int v) {
    union { unsigned int u; float f; } c; c.u = v & 0xffff0000u; return c.f;
}
__device__ __forceinline__ unsigned short f2bf(float f) {
    union { float f; unsigned int u; } c; c.f = f;
    unsigned int u = c.u;
    return (unsigned short)((u + 0x7fffu + ((u >> 16) & 1u)) >> 16);
}
__device__ __forceinline__ unsigned int pack2(float a, float b) {
    return (unsigned int)f2bf(a) | ((unsigned int)f2bf(b) << 16);
}

// ---------- graph prep ----------
__global__ void hist_k(const int* __restrict__ dst, int* __restrict__ cnt, int n) {
    int g = blockIdx.x * 256 + threadIdx.x;
    if (g < n) atomicAdd(&cnt[dst[g]], 1);
}

// block-level exclusive scan of cnt + dinv fused
__global__ void scanA_k(const int* __restrict__ cnt, int* __restrict__ off,
                        int* __restrict__ bsum, float* __restrict__ dinv, int n) {
    __shared__ int sh[256];
    int t = threadIdx.x;
    int g = blockIdx.x * 256 + t;
    int v = (g < n) ? cnt[g] : 0;
    if (g < n) dinv[g] = rsqrtf((float)(v + 1));  // +1 self-loop
    sh[t] = v; __syncthreads();
    for (int d = 1; d < 256; d <<= 1) {
        int x = (t >= d) ? sh[t - d] : 0; __syncthreads();
        sh[t] += x; __syncthreads();
    }
    if (g < n) off[g] = sh[t] - v;
    if (t == 255) bsum[blockIdx.x] = sh[255];
}

__global__ void scanB_k(int* __restrict__ bsum, int nb) {
    __shared__ int sh[256];
    int t = threadIdx.x;
    int v = (t < nb) ? bsum[t] : 0;
    sh[t] = v; __syncthreads();
    for (int d = 1; d < 256; d <<= 1) {
        int x = (t >= d) ? sh[t - d] : 0; __syncthreads();
        sh[t] += x; __syncthreads();
    }
    if (t < nb) bsum[t] = sh[t] - v;
}

// CSR fill; final offset = off[d] + bsum[d>>8] computed inline
__global__ void fill_k(const int* __restrict__ src, const int* __restrict__ dst,
                       const int* __restrict__ off, const int* __restrict__ bsum,
                       int* __restrict__ cur, unsigned short* __restrict__ csr, int n) {
    int g = blockIdx.x * 256 + threadIdx.x;
    if (g < n) {
        int d = dst[g];
        int p = atomicAdd(&cur[d], 1);
        csr[off[d] + bsum[d >> 8] + p] = (unsigned short)src[g];
    }
}

// ---------- weight transpose+convert: W[K][C] fp32 -> Wt[C][K] bf16 ----------
__global__ void wt_k(const float* __restrict__ w0, const float* __restrict__ w1,
                     const float* __restrict__ w2, const float* __restrict__ w3,
                     const float* __restrict__ w4, const float* __restrict__ w5,
                     const float* __restrict__ w6,
                     unsigned short* __restrict__ t0, unsigned short* __restrict__ t1,
                     unsigned short* __restrict__ t2, unsigned short* __restrict__ t3,
                     unsigned short* __restrict__ t4, unsigned short* __restrict__ t5,
                     unsigned short* __restrict__ t6)
{
    int b = blockIdx.x;
    const float* W; unsigned short* T; int K, C;
    if      (b <  32) { W = w0; T = t0; K =  64; C = 128; }
    else if (b <  96) { W = w1; T = t1; K = 128; C = 128; b -= 32; }
    else if (b < 160) { W = w2; T = t2; K = 128; C = 128; b -= 96; }
    else if (b < 224) { W = w3; T = t3; K = 128; C = 128; b -= 160; }
    else if (b < 288) { W = w4; T = t4; K = 128; C = 128; b -= 224; }
    else if (b < 352) { W = w5; T = t5; K = 128; C = 128; b -= 288; }
    else              { W = w6; T = t6; K = 128; C =  64; b -= 352; }
    int e = b * 256 + threadIdx.x;
    int k, n;
    if (C == 128) { k = e >> 7; n = e & 127; } else { k = e >> 6; n = e & 63; }
    T[n * K + k] = f2bf(W[e]);
}

// ---------- MFMA GEMM, register-resident W, no LDS, no barriers ----------
// out[N,COLS] = epi(A[N,K] @ W[K,COLS] * rowscale + bias)
// Column-split: wave w owns cols [w*COLS/4, (w+1)*COLS/4). W-frags loaded ONCE
// per block into VGPRs; block grid-strides over 64-row tiles. All 4 waves read
// the same A-frags (L1-shared). D-layout: row=q*4+r, col=m -> 32B-contig stores.
// EPI: 0=none, 1=relu, 2=sigmoid
template <int K, int COLS, int EPI, bool BIAS, bool RSCALE, bool A_F32, bool OUT_F32>
__global__ __launch_bounds__(256) void mgemm_k(
    const void* __restrict__ Av,
    const unsigned short* __restrict__ Wt,
    const float* __restrict__ bias,
    const float* __restrict__ dinv,
    void* __restrict__ outv, int nrows, int ntiles)
{
    constexpr int KC  = K / 32;      // k chunks (4 or 2)
    constexpr int NBW = COLS / 64;   // col-frags per wave (2 or 1)

    const int wave = threadIdx.x >> 6;
    const int lane = threadIdx.x & 63;
    const int m = lane & 15;
    const int q = lane >> 4;

    // W-frags: loaded once, live in registers for the whole kernel
    short8 wf[NBW][KC];
    float  bv[NBW];
    #pragma unroll
    for (int nb = 0; nb < NBW; nb++) {
        const int c = (wave * NBW + nb) * 16 + m;
        #pragma unroll
        for (int kc = 0; kc < KC; kc++)
            wf[nb][kc] = *(const short8*)(Wt + (size_t)c * K + kc * 32 + q * 8);
        bv[nb] = BIAS ? bias[c] : 0.f;
    }

    for (int tile = blockIdx.x; tile < ntiles; tile += gridDim.x) {
        const int base = tile * 64;

        // A-frags: 4 row-frags x KC chunks (operand-a layout: row=m, k=q*8+j)
        short8 af[4][KC];
        #pragma unroll
        for (int rf = 0; rf < 4; rf++) {
            const int row = base + rf * 16 + m;
            if constexpr (A_F32) {
                const bool ok = row < nrows;
                #pragma unroll
                for (int kc = 0; kc < KC; kc++) {
                    const float* p = (const float*)Av + (size_t)row * K + kc * 32 + q * 8;
                    float4 lo = make_float4(0.f, 0.f, 0.f, 0.f), hi = lo;
                    if (ok) { lo = *(const float4*)p; hi = *(const float4*)(p + 4); }
                    af[rf][kc][0] = (short)f2bf(lo.x); af[rf][kc][1] = (short)f2bf(lo.y);
                    af[rf][kc][2] = (short)f2bf(lo.z); af[rf][kc][3] = (short)f2bf(lo.w);
                    af[rf][kc][4] = (short)f2bf(hi.x); af[rf][kc][5] = (short)f2bf(hi.y);
                    af[rf][kc][6] = (short)f2bf(hi.z); af[rf][kc][7] = (short)f2bf(hi.w);
                }
            } else {
                #pragma unroll
                for (int kc = 0; kc < KC; kc++)
                    af[rf][kc] = *(const short8*)((const unsigned short*)Av +
                                  (size_t)row * K + kc * 32 + q * 8);
            }
        }

        f32x4 acc[4][NBW];
        #pragma unroll
        for (int rf = 0; rf < 4; rf++)
            #pragma unroll
            for (int nb = 0; nb < NBW; nb++) acc[rf][nb] = (f32x4){0.f, 0.f, 0.f, 0.f};

        #pragma unroll
        for (int kc = 0; kc < KC; kc++)
            #pragma unroll
            for (int rf = 0; rf < 4; rf++)
                #pragma unroll
                for (int nb = 0; nb < NBW; nb++)
                    acc[rf][nb] = __builtin_amdgcn_mfma_f32_16x16x32_bf16(
                        af[rf][kc], wf[nb][kc], acc[rf][nb], 0, 0, 0);

        // epilogue: D row=q*4+r (node), col=m within col-frag
        #pragma unroll
        for (int rf = 0; rf < 4; rf++) {
            #pragma unroll
            for (int r = 0; r < 4; r++) {
                const int row = base + rf * 16 + q * 4 + r;
                if (row < nrows) {
                    const float sc = RSCALE ? dinv[row] : 1.f;
                    #pragma unroll
                    for (int nb = 0; nb < NBW; nb++) {
                        float t = acc[rf][nb][r];
                        if (RSCALE) t *= sc;
                        t += bv[nb];
                        if (EPI == 1) t = fmaxf(t, 0.f);
                        if (EPI == 2) t = 1.f / (1.f + __expf(-t));
                        const int col = (wave * NBW + nb) * 16 + m;
                        if constexpr (OUT_F32)
                            ((float*)outv)[(size_t)row * COLS + col] = t;
                        else
                            ((unsigned short*)outv)[(size_t)row * COLS + col] = f2bf(t);
                    }
                }
            }
        }
    }
}

// ---------- GCN aggregation: out[d] = relu(dinv[d]*(hws[d] + sum_in hws[s]) + b) ----------
// half-wave (32 lanes) per node; lane owns features {4l..4l+3} as uint2 (bf16x4)
__global__ __launch_bounds__(256) void agg_k(
    const uint2* __restrict__ hws,  // [N][32] uint2
    const int* __restrict__ off, const int* __restrict__ bsum,
    const unsigned short* __restrict__ csr,
    const float* __restrict__ dinv, const float* __restrict__ bias,
    uint2* __restrict__ out, int n)
{
    int node = blockIdx.x * 8 + (threadIdx.x >> 5);
    if (node >= n) return;
    int lane = threadIdx.x & 31;

    uint2 v = hws[node * 32 + lane];  // self-loop term
    float s0 = bflo(v.x), s1 = bfhi(v.x), s2 = bflo(v.y), s3 = bfhi(v.y);

    int b = off[node] + bsum[node >> 8];
    int e = (node + 1 < n) ? (off[node + 1] + bsum[(node + 1) >> 8]) : NE;
    int j = b;
    for (; j + 8 <= e; j += 8) {
        uint2 t[8];
        #pragma unroll
        for (int u = 0; u < 8; u++) t[u] = hws[(int)csr[j + u] * 32 + lane];
        #pragma unroll
        for (int u = 0; u < 8; u++) {
            s0 += bflo(t[u].x); s1 += bfhi(t[u].x);
            s2 += bflo(t[u].y); s3 += bfhi(t[u].y);
        }
    }
    for (; j < e; j++) {
        uint2 t = hws[(int)csr[j] * 32 + lane];
        s0 += bflo(t.x); s1 += bfhi(t.x);
        s2 += bflo(t.y); s3 += bfhi(t.y);
    }

    float di = dinv[node];
    float4 bv = *(const float4*)(bias + 4 * lane);
    float r0 = fmaxf(fmaf(di, s0, bv.x), 0.f);
    float r1 = fmaxf(fmaf(di, s1, bv.y), 0.f);
    float r2 = fmaxf(fmaf(di, s2, bv.z), 0.f);
    float r3 = fmaxf(fmaf(di, s3, bv.w), 0.f);
    uint2 o; o.x = pack2(r0, r1); o.y = pack2(r2, r3);
    out[node * 32 + lane] = o;
}

// ---------- launch ----------
extern "C" void kernel_launch(void* const* d_in, const int* in_sizes, int n_in,
                              void* d_out, int out_size, void* d_ws, size_t ws_size,
                              hipStream_t stream)
{
    const float* x      = (const float*)d_in[0];
    const int*   ei     = (const int*)d_in[1];
    const float* enc_w1 = (const float*)d_in[2];
    const float* enc_b1 = (const float*)d_in[3];
    const float* enc_w2 = (const float*)d_in[4];
    const float* enc_b2 = (const float*)d_in[5];
    const float* w_c1   = (const float*)d_in[6];
    const float* b_c1   = (const float*)d_in[7];
    const float* w_c2   = (const float*)d_in[8];
    const float* b_c2   = (const float*)d_in[9];
    const float* w_c3   = (const float*)d_in[10];
    const float* b_c3   = (const float*)d_in[11];
    const float* dec_w1 = (const float*)d_in[12];
    const float* dec_b1 = (const float*)d_in[13];
    const float* dec_w2 = (const float*)d_in[14];
    const float* dec_b2 = (const float*)d_in[15];

    const int* src = ei;
    const int* dst = ei + NE;

    const int NP = 50048;         // rows padded to multiple of 64
    const int NT = NP / 64;       // 782 row-tiles
    const int MG = 512;           // mgemm grid (2 blocks/CU)

    char* ws = (char*)d_ws;
    size_t o = 0;
    auto alloc = [&](size_t bytes) -> void* {
        void* p = ws + o;
        o = (o + bytes + 255) & ~(size_t)255;
        return p;
    };
    int*   cnt  = (int*)alloc((size_t)NN * 4);
    int*   cur  = (int*)alloc((size_t)NN * 4);
    int*   off  = (int*)alloc((size_t)(NN + 1) * 4);
    int*   bsum = (int*)alloc(256 * 4);
    unsigned short* csr = (unsigned short*)alloc((size_t)NE * 2);
    float* dinv = (float*)alloc((size_t)NN * 4);
    unsigned short* bufA = (unsigned short*)alloc((size_t)NP * HD * 2);
    unsigned short* bufB = (unsigned short*)alloc((size_t)NP * HD * 2);
    unsigned short* t0 = (unsigned short*)alloc(64 * 128 * 2);   // enc_w1^T
    unsigned short* t1 = (unsigned short*)alloc(128 * 128 * 2);  // enc_w2^T
    unsigned short* t2 = (unsigned short*)alloc(128 * 128 * 2);  // w_c1^T
    unsigned short* t3 = (unsigned short*)alloc(128 * 128 * 2);  // w_c2^T
    unsigned short* t4 = (unsigned short*)alloc(128 * 128 * 2);  // w_c3^T
    unsigned short* t5 = (unsigned short*)alloc(128 * 128 * 2);  // dec_w1^T
    unsigned short* t6 = (unsigned short*)alloc(128 * 64 * 2);   // dec_w2^T
    (void)ws_size; (void)n_in; (void)in_sizes; (void)out_size;

    hipMemsetAsync(cnt, 0, (size_t)NN * 4, stream);
    hipMemsetAsync(cur, 0, (size_t)NN * 4, stream);

    const int EB = (NE + 255) / 256;
    const int NB_ = (NN + 255) / 256;
    hist_k<<<EB, 256, 0, stream>>>(dst, cnt, NE);
    scanA_k<<<NB_, 256, 0, stream>>>(cnt, off, bsum, dinv, NN);
    scanB_k<<<1, 256, 0, stream>>>(bsum, NB_);
    fill_k<<<EB, 256, 0, stream>>>(src, dst, off, bsum, cur, csr, NE);
    wt_k<<<384, 256, 0, stream>>>(enc_w1, enc_w2, w_c1, w_c2, w_c3, dec_w1, dec_w2,
                                  t0, t1, t2, t3, t4, t5, t6);

    const int AB = (NN + 7) / 8;      // 6250 agg blocks

    // encoder
    mgemm_k<64, 128, 1, true, false, true, false><<<MG, 256, 0, stream>>>(x, t0, enc_b1, nullptr, bufA, NN, NT);
    mgemm_k<128, 128, 0, true, false, false, false><<<MG, 256, 0, stream>>>(bufA, t1, enc_b2, nullptr, bufB, NN, NT);
    // conv1
    mgemm_k<128, 128, 0, false, true, false, false><<<MG, 256, 0, stream>>>(bufB, t2, nullptr, dinv, bufA, NN, NT);
    agg_k<<<AB, 256, 0, stream>>>((const uint2*)bufA, off, bsum, csr, dinv, b_c1, (uint2*)bufB, NN);
    // conv2
    mgemm_k<128, 128, 0, false, true, false, false><<<MG, 256, 0, stream>>>(bufB, t3, nullptr, dinv, bufA, NN, NT);
    agg_k<<<AB, 256, 0, stream>>>((const uint2*)bufA, off, bsum, csr, dinv, b_c2, (uint2*)bufB, NN);
    // conv3
    mgemm_k<128, 128, 0, false, true, false, false><<<MG, 256, 0, stream>>>(bufB, t4, nullptr, dinv, bufA, NN, NT);
    agg_k<<<AB, 256, 0, stream>>>((const uint2*)bufA, off, bsum, csr, dinv, b_c3, (uint2*)bufB, NN);
    // decoder
    mgemm_k<128, 128, 1, true, false, false, false><<<MG, 256, 0, stream>>>(bufB, t5, dec_b1, nullptr, bufA, NN, NT);
    mgemm_k<128, 64, 2, true, false, false, true><<<MG, 256, 0, stream>>>(bufA, t6, dec_b2, nullptr, d_out, NN, NT);
}

// Round 8
// 341.928 us; speedup vs baseline: 1.1456x; 1.1456x over previous
//
#include <hip/hip_runtime.h>
#include <stdint.h>

#define NN 50000
#define NE 800000
#define FD 64
#define HD 128

typedef __attribute__((ext_vector_type(8))) short short8;   // 8 bf16 (4 VGPRs)
typedef __attribute__((ext_vector_type(4))) float f32x4;    // MFMA acc

#define AS1 __attribute__((address_space(1)))
#define AS3 __attribute__((address_space(3)))

// ---------- bf16 helpers ----------
__device__ __forceinline__ float bflo(unsigned int v) {
    union { unsigned int u; float f; } c; c.u = v << 16; return c.f;
}
__device__ __forceinline__ float bfhi(unsigned int v) {
    union { unsigned int u; float f; } c; c.u = v & 0xffff0000u; return c.f;
}
__device__ __forceinline__ unsigned short f2bf(float f) {
    union { float f; unsigned int u; } c; c.f = f;
    unsigned int u = c.u;
    return (unsigned short)((u + 0x7fffu + ((u >> 16) & 1u)) >> 16);
}
__device__ __forceinline__ unsigned int pack2(float a, float b) {
    return (unsigned int)f2bf(a) | ((unsigned int)f2bf(b) << 16);
}

// ---------- merged: edge histogram + weight transpose/convert/swizzle ----------
// blocks [0, HB): histogram of dst
// blocks [HB, HB+384): Wt build. Wt[c][K] bf16, with 16B-granule XOR swizzle:
//   element (k, c) -> T[c*K + ((k>>3) ^ (c & (K/8-1)))*8 + (k&7)]
// so that a LINEAR global_load_lds image gives conflict-free swizzled ds_reads.
__global__ void histwt_k(const int* __restrict__ dst, int* __restrict__ cnt, int hb,
                         const float* __restrict__ w0, const float* __restrict__ w1,
                         const float* __restrict__ w2, const float* __restrict__ w3,
                         const float* __restrict__ w4, const float* __restrict__ w5,
                         const float* __restrict__ w6,
                         unsigned short* __restrict__ t0, unsigned short* __restrict__ t1,
                         unsigned short* __restrict__ t2, unsigned short* __restrict__ t3,
                         unsigned short* __restrict__ t4, unsigned short* __restrict__ t5,
                         unsigned short* __restrict__ t6)
{
    if (blockIdx.x < (unsigned)hb) {
        int g = blockIdx.x * 256 + threadIdx.x;
        if (g < NE) atomicAdd(&cnt[dst[g]], 1);
        return;
    }
    int b = blockIdx.x - hb;
    const float* W; unsigned short* T; int K, C;
    if      (b <  32) { W = w0; T = t0; K =  64; C = 128; }
    else if (b <  96) { W = w1; T = t1; K = 128; C = 128; b -= 32; }
    else if (b < 160) { W = w2; T = t2; K = 128; C = 128; b -= 96; }
    else if (b < 224) { W = w3; T = t3; K = 128; C = 128; b -= 160; }
    else if (b < 288) { W = w4; T = t4; K = 128; C = 128; b -= 224; }
    else if (b < 352) { W = w5; T = t5; K = 128; C = 128; b -= 288; }
    else              { W = w6; T = t6; K = 128; C =  64; b -= 352; }
    int e = b * 256 + threadIdx.x;
    int k, c;
    if (C == 128) { k = e >> 7; c = e & 127; } else { k = e >> 6; c = e & 63; }
    int gmask = (K >> 3) - 1;
    int gsw = (k >> 3) ^ (c & gmask);
    T[c * K + gsw * 8 + (k & 7)] = f2bf(W[e]);
}

// block-level exclusive scan of cnt + dinv fused
__global__ void scanA_k(const int* __restrict__ cnt, int* __restrict__ off,
                        int* __restrict__ bsum, float* __restrict__ dinv, int n) {
    __shared__ int sh[256];
    int t = threadIdx.x;
    int g = blockIdx.x * 256 + t;
    int v = (g < n) ? cnt[g] : 0;
    if (g < n) dinv[g] = rsqrtf((float)(v + 1));  // +1 self-loop
    sh[t] = v; __syncthreads();
    for (int d = 1; d < 256; d <<= 1) {
        int x = (t >= d) ? sh[t - d] : 0; __syncthreads();
        sh[t] += x; __syncthreads();
    }
    if (g < n) off[g] = sh[t] - v;
    if (t == 255) bsum[blockIdx.x] = sh[255];
}

__global__ void scanB_k(int* __restrict__ bsum, int nb) {
    __shared__ int sh[256];
    int t = threadIdx.x;
    int v = (t < nb) ? bsum[t] : 0;
    sh[t] = v; __syncthreads();
    for (int d = 1; d < 256; d <<= 1) {
        int x = (t >= d) ? sh[t - d] : 0; __syncthreads();
        sh[t] += x; __syncthreads();
    }
    if (t < nb) bsum[t] = sh[t] - v;
}

// CSR fill; final offset = off[d] + bsum[d>>8] computed inline
__global__ void fill_k(const int* __restrict__ src, const int* __restrict__ dst,
                       const int* __restrict__ off, const int* __restrict__ bsum,
                       int* __restrict__ cur, unsigned short* __restrict__ csr, int n) {
    int g = blockIdx.x * 256 + threadIdx.x;
    if (g < n) {
        int d = dst[g];
        int p = atomicAdd(&cur[d], 1);
        csr[off[d] + bsum[d >> 8] + p] = (unsigned short)src[g];
    }
}

// ---------- MFMA GEMM: out[N,COLS] = epi(A[N,K] @ W[K,COLS] * rowscale + bias) ----------
// Wt staged to LDS via global_load_lds width=16 (no VGPR round-trip); image is
// linear (Wt pre-swizzled in histwt_k), ds_read uses XOR-granule addressing ->
// bank groups spread, 2-way max (free). EPI: 0=none, 1=relu, 2=sigmoid
template <int K, int COLS, int EPI, bool BIAS, bool RSCALE, bool A_F32, bool OUT_F32>
__global__ __launch_bounds__(256) void mgemm_k(
    const void* __restrict__ Av,
    const unsigned short* __restrict__ Wt,
    const float* __restrict__ bias,
    const float* __restrict__ dinv,
    void* __restrict__ outv, int nrows)
{
    constexpr int NB = COLS / 16;   // col frags per wave (8 or 4)
    constexpr int KC = K / 32;      // k chunks (4 or 2)
    constexpr int GMASK = (K >> 3) - 1;
    __shared__ __align__(16) unsigned char Ws8[COLS * K * 2];

    const int tid = threadIdx.x;
    const int wave = tid >> 6;
    const int lane = tid & 63;

    // stage Wt -> LDS, linear image, 16B per lane per round
    {
        constexpr int ROUNDS = COLS * K * 2 / 4096;
        const int gb = wave * 1024 + lane * 16;  // per-lane global byte offset
        const int lb = wave * 1024;              // wave-uniform LDS byte offset
        #pragma unroll
        for (int r = 0; r < ROUNDS; r++) {
            __builtin_amdgcn_global_load_lds(
                (const AS1 unsigned int*)((const unsigned char*)Wt + r * 4096 + gb),
                (AS3 unsigned int*)(Ws8 + r * 4096 + lb),
                16, 0, 0);
        }
    }

    const int m = lane & 15;        // A-row / W-col index within frag
    const int q = lane >> 4;        // quad: k-offset q*8 (A/B), row-base q*4 (C)
    const int row0 = blockIdx.x * 64 + wave * 16;

    f32x4 acc[NB];
    #pragma unroll
    for (int i = 0; i < NB; i++) acc[i] = (f32x4){0.f, 0.f, 0.f, 0.f};

    const bool arow_ok = !A_F32 || (row0 + m) < nrows;

    // prefetch A frags (independent of LDS staging)
    short8 af[KC];
    #pragma unroll
    for (int kc = 0; kc < KC; kc++) {
        if constexpr (A_F32) {
            const float* arowf = (const float*)Av + (size_t)(row0 + m) * K + q * 8 + kc * 32;
            float4 lo = make_float4(0.f, 0.f, 0.f, 0.f), hi = lo;
            if (arow_ok) { lo = *(const float4*)arowf; hi = *(const float4*)(arowf + 4); }
            af[kc][0] = (short)f2bf(lo.x); af[kc][1] = (short)f2bf(lo.y);
            af[kc][2] = (short)f2bf(lo.z); af[kc][3] = (short)f2bf(lo.w);
            af[kc][4] = (short)f2bf(hi.x); af[kc][5] = (short)f2bf(hi.y);
            af[kc][6] = (short)f2bf(hi.z); af[kc][7] = (short)f2bf(hi.w);
        } else {
            const unsigned short* arow = (const unsigned short*)Av + (size_t)(row0 + m) * K + q * 8 + kc * 32;
            af[kc] = *(const short8*)arow;
        }
    }
    __syncthreads();

    #pragma unroll
    for (int kc = 0; kc < KC; kc++) {
        #pragma unroll
        for (int nb = 0; nb < NB; nb++) {
            const int c = nb * 16 + m;
            const int gsw = (kc * 4 + q) ^ (c & GMASK);
            short8 bf = *(const short8*)&Ws8[(c * K + gsw * 8) * 2];
            acc[nb] = __builtin_amdgcn_mfma_f32_16x16x32_bf16(af[kc], bf, acc[nb], 0, 0, 0);
        }
    }

    float bv[NB];
    #pragma unroll
    for (int nb = 0; nb < NB; nb++) bv[nb] = BIAS ? bias[nb * 16 + m] : 0.f;

    #pragma unroll
    for (int r = 0; r < 4; r++) {
        int row = row0 + q * 4 + r;
        if (row < nrows) {
            float sc = RSCALE ? dinv[row] : 1.f;
            #pragma unroll
            for (int nb = 0; nb < NB; nb++) {
                float t = acc[nb][r];
                if (RSCALE) t *= sc;
                t += bv[nb];
                if (EPI == 1) t = fmaxf(t, 0.f);
                if (EPI == 2) t = 1.f / (1.f + __expf(-t));
                if constexpr (OUT_F32) {
                    ((float*)outv)[(size_t)row * COLS + nb * 16 + m] = t;
                } else {
                    ((unsigned short*)outv)[(size_t)row * COLS + nb * 16 + m] = f2bf(t);
                }
            }
        }
    }
}

// ---------- GCN aggregation: out[d] = relu(dinv[d]*(hws[d] + sum_in hws[s]) + b) ----------
// half-wave (32 lanes) per node; lane owns features {4l..4l+3} as uint2 (bf16x4)
__global__ __launch_bounds__(256) void agg_k(
    const uint2* __restrict__ hws,  // [N][32] uint2
    const int* __restrict__ off, const int* __restrict__ bsum,
    const unsigned short* __restrict__ csr,
    const float* __restrict__ dinv, const float* __restrict__ bias,
    uint2* __restrict__ out, int n)
{
    int node = blockIdx.x * 8 + (threadIdx.x >> 5);
    if (node >= n) return;
    int lane = threadIdx.x & 31;

    uint2 v = hws[node * 32 + lane];  // self-loop term
    float s0 = bflo(v.x), s1 = bfhi(v.x), s2 = bflo(v.y), s3 = bfhi(v.y);

    int b = off[node] + bsum[node >> 8];
    int e = (node + 1 < n) ? (off[node + 1] + bsum[(node + 1) >> 8]) : NE;
    int j = b;
    for (; j + 8 <= e; j += 8) {
        uint2 t[8];
        #pragma unroll
        for (int u = 0; u < 8; u++) t[u] = hws[(int)csr[j + u] * 32 + lane];
        #pragma unroll
        for (int u = 0; u < 8; u++) {
            s0 += bflo(t[u].x); s1 += bfhi(t[u].x);
            s2 += bflo(t[u].y); s3 += bfhi(t[u].y);
        }
    }
    for (; j < e; j++) {
        uint2 t = hws[(int)csr[j] * 32 + lane];
        s0 += bflo(t.x); s1 += bfhi(t.x);
        s2 += bflo(t.y); s3 += bfhi(t.y);
    }

    float di = dinv[node];
    float4 bv = *(const float4*)(bias + 4 * lane);
    float r0 = fmaxf(fmaf(di, s0, bv.x), 0.f);
    float r1 = fmaxf(fmaf(di, s1, bv.y), 0.f);
    float r2 = fmaxf(fmaf(di, s2, bv.z), 0.f);
    float r3 = fmaxf(fmaf(di, s3, bv.w), 0.f);
    uint2 o; o.x = pack2(r0, r1); o.y = pack2(r2, r3);
    out[node * 32 + lane] = o;
}

// ---------- launch ----------
extern "C" void kernel_launch(void* const* d_in, const int* in_sizes, int n_in,
                              void* d_out, int out_size, void* d_ws, size_t ws_size,
                              hipStream_t stream)
{
    const float* x      = (const float*)d_in[0];
    const int*   ei     = (const int*)d_in[1];
    const float* enc_w1 = (const float*)d_in[2];
    const float* enc_b1 = (const float*)d_in[3];
    const float* enc_w2 = (const float*)d_in[4];
    const float* enc_b2 = (const float*)d_in[5];
    const float* w_c1   = (const float*)d_in[6];
    const float* b_c1   = (const float*)d_in[7];
    const float* w_c2   = (const float*)d_in[8];
    const float* b_c2   = (const float*)d_in[9];
    const float* w_c3   = (const float*)d_in[10];
    const float* b_c3   = (const float*)d_in[11];
    const float* dec_w1 = (const float*)d_in[12];
    const float* dec_b1 = (const float*)d_in[13];
    const float* dec_w2 = (const float*)d_in[14];
    const float* dec_b2 = (const float*)d_in[15];

    const int* src = ei;
    const int* dst = ei + NE;

    const int NP = 50048;  // rows padded to multiple of 64

    char* ws = (char*)d_ws;
    size_t o = 0;
    auto alloc = [&](size_t bytes) -> void* {
        void* p = ws + o;
        o = (o + bytes + 255) & ~(size_t)255;
        return p;
    };
    int*   cnt  = (int*)alloc((size_t)NN * 4);   // cnt and cur adjacent: one memset
    int*   cur  = (int*)alloc((size_t)NN * 4);
    int*   off  = (int*)alloc((size_t)(NN + 1) * 4);
    int*   bsum = (int*)alloc(256 * 4);
    unsigned short* csr = (unsigned short*)alloc((size_t)NE * 2);
    float* dinv = (float*)alloc((size_t)NN * 4);
    unsigned short* bufA = (unsigned short*)alloc((size_t)NP * HD * 2);
    unsigned short* bufB = (unsigned short*)alloc((size_t)NP * HD * 2);
    unsigned short* t0 = (unsigned short*)alloc(64 * 128 * 2);   // enc_w1^T (swizzled)
    unsigned short* t1 = (unsigned short*)alloc(128 * 128 * 2);  // enc_w2^T
    unsigned short* t2 = (unsigned short*)alloc(128 * 128 * 2);  // w_c1^T
    unsigned short* t3 = (unsigned short*)alloc(128 * 128 * 2);  // w_c2^T
    unsigned short* t4 = (unsigned short*)alloc(128 * 128 * 2);  // w_c3^T
    unsigned short* t5 = (unsigned short*)alloc(128 * 128 * 2);  // dec_w1^T
    unsigned short* t6 = (unsigned short*)alloc(128 * 64 * 2);   // dec_w2^T
    (void)ws_size; (void)n_in; (void)in_sizes; (void)out_size;

    // single memset covers cnt + cur (adjacent, 256-aligned)
    hipMemsetAsync(cnt, 0, (size_t)((char*)cur - (char*)cnt) + (size_t)NN * 4, stream);

    const int HB = (NE + 255) / 256;   // 3125 hist blocks
    const int NB_ = (NN + 255) / 256;  // 196
    histwt_k<<<HB + 384, 256, 0, stream>>>(dst, cnt, HB,
                                           enc_w1, enc_w2, w_c1, w_c2, w_c3, dec_w1, dec_w2,
                                           t0, t1, t2, t3, t4, t5, t6);
    scanA_k<<<NB_, 256, 0, stream>>>(cnt, off, bsum, dinv, NN);
    scanB_k<<<1, 256, 0, stream>>>(bsum, NB_);
    fill_k<<<HB, 256, 0, stream>>>(src, dst, off, bsum, cur, csr, NE);

    const int GB = NP / 64;           // 782 row-tiles
    const int AB = (NN + 7) / 8;      // 6250 agg blocks

    // encoder
    mgemm_k<64, 128, 1, true, false, true, false><<<GB, 256, 0, stream>>>(x, t0, enc_b1, nullptr, bufA, NN);
    mgemm_k<128, 128, 0, true, false, false, false><<<GB, 256, 0, stream>>>(bufA, t1, enc_b2, nullptr, bufB, NN);
    // conv1
    mgemm_k<128, 128, 0, false, true, false, false><<<GB, 256, 0, stream>>>(bufB, t2, nullptr, dinv, bufA, NN);
    agg_k<<<AB, 256, 0, stream>>>((const uint2*)bufA, off, bsum, csr, dinv, b_c1, (uint2*)bufB, NN);
    // conv2
    mgemm_k<128, 128, 0, false, true, false, false><<<GB, 256, 0, stream>>>(bufB, t3, nullptr, dinv, bufA, NN);
    agg_k<<<AB, 256, 0, stream>>>((const uint2*)bufA, off, bsum, csr, dinv, b_c2, (uint2*)bufB, NN);
    // conv3
    mgemm_k<128, 128, 0, false, true, false, false><<<GB, 256, 0, stream>>>(bufB, t4, nullptr, dinv, bufA, NN);
    agg_k<<<AB, 256, 0, stream>>>((const uint2*)bufA, off, bsum, csr, dinv, b_c3, (uint2*)bufB, NN);
    // decoder
    mgemm_k<128, 128, 1, true, false, false, false><<<GB, 256, 0, stream>>>(bufB, t5, dec_b1, nullptr, bufA, NN);
    mgemm_k<128, 64, 2, true, false, false, true><<<GB, 256, 0, stream>>>(bufA, t6, dec_b2, nullptr, d_out, NN);
}

// Round 9
// 332.661 us; speedup vs baseline: 1.1775x; 1.0279x over previous
//
#include <hip/hip_runtime.h>
#include <stdint.h>

#define NN 50000
#define NE 800000
#define FD 64
#define HD 128

typedef __attribute__((ext_vector_type(8))) short short8;   // 8 bf16 (4 VGPRs)
typedef __attribute__((ext_vector_type(4))) float f32x4;    // MFMA acc

#define AS1 __attribute__((address_space(1)))
#define AS3 __attribute__((address_space(3)))

// ---------- bf16 helpers ----------
__device__ __forceinline__ float bflo(unsigned int v) {
    union { unsigned int u; float f; } c; c.u = v << 16; return c.f;
}
__device__ __forceinline__ float bfhi(unsigned int v) {
    union { unsigned int u; float f; } c; c.u = v & 0xffff0000u; return c.f;
}
__device__ __forceinline__ unsigned short f2bf(float f) {
    union { float f; unsigned int u; } c; c.f = f;
    unsigned int u = c.u;
    return (unsigned short)((u + 0x7fffu + ((u >> 16) & 1u)) >> 16);
}
__device__ __forceinline__ unsigned int pack2(float a, float b) {
    return (unsigned int)f2bf(a) | ((unsigned int)f2bf(b) << 16);
}

// ---------- weight transpose/convert/swizzle: W[K][C] fp32 -> Wt[c][K] bf16 ----------
// 16B-granule XOR swizzle: (k,c) -> T[c*K + ((k>>3) ^ (c & (K/8-1)))*8 + (k&7)]
__global__ void wt_k(const float* __restrict__ w0, const float* __restrict__ w1,
                     const float* __restrict__ w2, const float* __restrict__ w3,
                     const float* __restrict__ w4, const float* __restrict__ w5,
                     const float* __restrict__ w6,
                     unsigned short* __restrict__ t0, unsigned short* __restrict__ t1,
                     unsigned short* __restrict__ t2, unsigned short* __restrict__ t3,
                     unsigned short* __restrict__ t4, unsigned short* __restrict__ t5,
                     unsigned short* __restrict__ t6)
{
    int b = blockIdx.x;
    const float* W; unsigned short* T; int K, C;
    if      (b <  32) { W = w0; T = t0; K =  64; C = 128; }
    else if (b <  96) { W = w1; T = t1; K = 128; C = 128; b -= 32; }
    else if (b < 160) { W = w2; T = t2; K = 128; C = 128; b -= 96; }
    else if (b < 224) { W = w3; T = t3; K = 128; C = 128; b -= 160; }
    else if (b < 288) { W = w4; T = t4; K = 128; C = 128; b -= 224; }
    else if (b < 352) { W = w5; T = t5; K = 128; C = 128; b -= 288; }
    else              { W = w6; T = t6; K = 128; C =  64; b -= 352; }
    int e = b * 256 + threadIdx.x;
    int k, c;
    if (C == 128) { k = e >> 7; c = e & 127; } else { k = e >> 6; c = e & 63; }
    int gmask = (K >> 3) - 1;
    int gsw = (k >> 3) ^ (c & gmask);
    T[c * K + gsw * 8 + (k & 7)] = f2bf(W[e]);
}

__global__ void scanB_k(int* __restrict__ bsum, int nb) {
    __shared__ int sh[256];
    int t = threadIdx.x;
    int v = (t < nb) ? bsum[t] : 0;
    sh[t] = v; __syncthreads();
    for (int d = 1; d < 256; d <<= 1) {
        int x = (t >= d) ? sh[t - d] : 0; __syncthreads();
        sh[t] += x; __syncthreads();
    }
    if (t < nb) bsum[t] = sh[t] - v;
}

// ---------- MFMA GEMM device body (block id passed in) ----------
// Wt staged to LDS via global_load_lds width=16; linear image (pre-swizzled),
// XOR-granule ds_read addressing -> conflict-free. EPI: 0=none 1=relu 2=sigmoid
template <int K, int COLS, int EPI, bool BIAS, bool RSCALE, bool A_F32, bool OUT_F32>
__device__ __forceinline__ void mgemm_dev(
    int bid,
    const void* __restrict__ Av,
    const unsigned short* __restrict__ Wt,
    const float* __restrict__ bias,
    const float* __restrict__ dinv,
    void* __restrict__ outv, int nrows)
{
    constexpr int NB = COLS / 16;
    constexpr int KC = K / 32;
    constexpr int GMASK = (K >> 3) - 1;
    __shared__ __align__(16) unsigned char Ws8[COLS * K * 2];

    const int tid = threadIdx.x;
    const int wave = tid >> 6;
    const int lane = tid & 63;

    {
        constexpr int ROUNDS = COLS * K * 2 / 4096;
        const int gb = wave * 1024 + lane * 16;
        const int lb = wave * 1024;
        #pragma unroll
        for (int r = 0; r < ROUNDS; r++) {
            __builtin_amdgcn_global_load_lds(
                (const AS1 unsigned int*)((const unsigned char*)Wt + r * 4096 + gb),
                (AS3 unsigned int*)(Ws8 + r * 4096 + lb),
                16, 0, 0);
        }
    }

    const int m = lane & 15;
    const int q = lane >> 4;
    const int row0 = bid * 64 + wave * 16;

    f32x4 acc[NB];
    #pragma unroll
    for (int i = 0; i < NB; i++) acc[i] = (f32x4){0.f, 0.f, 0.f, 0.f};

    const bool arow_ok = !A_F32 || (row0 + m) < nrows;

    short8 af[KC];
    #pragma unroll
    for (int kc = 0; kc < KC; kc++) {
        if constexpr (A_F32) {
            const float* arowf = (const float*)Av + (size_t)(row0 + m) * K + q * 8 + kc * 32;
            float4 lo = make_float4(0.f, 0.f, 0.f, 0.f), hi = lo;
            if (arow_ok) { lo = *(const float4*)arowf; hi = *(const float4*)(arowf + 4); }
            af[kc][0] = (short)f2bf(lo.x); af[kc][1] = (short)f2bf(lo.y);
            af[kc][2] = (short)f2bf(lo.z); af[kc][3] = (short)f2bf(lo.w);
            af[kc][4] = (short)f2bf(hi.x); af[kc][5] = (short)f2bf(hi.y);
            af[kc][6] = (short)f2bf(hi.z); af[kc][7] = (short)f2bf(hi.w);
        } else {
            const unsigned short* arow = (const unsigned short*)Av + (size_t)(row0 + m) * K + q * 8 + kc * 32;
            af[kc] = *(const short8*)arow;
        }
    }
    __syncthreads();

    #pragma unroll
    for (int kc = 0; kc < KC; kc++) {
        #pragma unroll
        for (int nb = 0; nb < NB; nb++) {
            const int c = nb * 16 + m;
            const int gsw = (kc * 4 + q) ^ (c & GMASK);
            short8 bf = *(const short8*)&Ws8[(c * K + gsw * 8) * 2];
            acc[nb] = __builtin_amdgcn_mfma_f32_16x16x32_bf16(af[kc], bf, acc[nb], 0, 0, 0);
        }
    }

    float bv[NB];
    #pragma unroll
    for (int nb = 0; nb < NB; nb++) bv[nb] = BIAS ? bias[nb * 16 + m] : 0.f;

    #pragma unroll
    for (int r = 0; r < 4; r++) {
        int row = row0 + q * 4 + r;
        if (row < nrows) {
            float sc = RSCALE ? dinv[row] : 1.f;
            #pragma unroll
            for (int nb = 0; nb < NB; nb++) {
                float t = acc[nb][r];
                if (RSCALE) t *= sc;
                t += bv[nb];
                if (EPI == 1) t = fmaxf(t, 0.f);
                if (EPI == 2) t = 1.f / (1.f + __expf(-t));
                if constexpr (OUT_F32) {
                    ((float*)outv)[(size_t)row * COLS + nb * 16 + m] = t;
                } else {
                    ((unsigned short*)outv)[(size_t)row * COLS + nb * 16 + m] = f2bf(t);
                }
            }
        }
    }
}

// plain mgemm wrapper
template <int K, int COLS, int EPI, bool BIAS, bool RSCALE, bool A_F32, bool OUT_F32>
__global__ __launch_bounds__(256) void mgemm_k(
    const void* __restrict__ Av, const unsigned short* __restrict__ Wt,
    const float* __restrict__ bias, const float* __restrict__ dinv,
    void* __restrict__ outv, int nrows)
{
    mgemm_dev<K, COLS, EPI, BIAS, RSCALE, A_F32, OUT_F32>(blockIdx.x, Av, Wt, bias, dinv, outv, nrows);
}

// ---------- K1: enc1-mgemm (blocks [0,gb)) ∥ dst-histogram (blocks [gb,...)) ----------
__global__ __launch_bounds__(256) void k1_k(
    const float* __restrict__ x, const unsigned short* __restrict__ t0,
    const float* __restrict__ enc_b1, unsigned short* __restrict__ bufA,
    const int* __restrict__ dst, int* __restrict__ cnt, int gb)
{
    if ((int)blockIdx.x < gb) {
        mgemm_dev<64, 128, 1, true, false, true, false>(blockIdx.x, x, t0, enc_b1, nullptr, bufA, NN);
    } else {
        int g = (blockIdx.x - gb) * 256 + threadIdx.x;
        if (g < NE) atomicAdd(&cnt[dst[g]], 1);
    }
}

// ---------- K2: enc2-mgemm ∥ scanA (block scan of cnt + dinv) ----------
__global__ __launch_bounds__(256) void k2_k(
    const unsigned short* __restrict__ bufA, const unsigned short* __restrict__ t1,
    const float* __restrict__ enc_b2, unsigned short* __restrict__ bufB,
    const int* __restrict__ cnt, int* __restrict__ off, int* __restrict__ bsum,
    float* __restrict__ dinv, int gb)
{
    if ((int)blockIdx.x < gb) {
        mgemm_dev<128, 128, 0, true, false, false, false>(blockIdx.x, bufA, t1, enc_b2, nullptr, bufB, NN);
    } else {
        __shared__ int sh[256];
        int t = threadIdx.x;
        int g = (blockIdx.x - gb) * 256 + t;
        int v = (g < NN) ? cnt[g] : 0;
        if (g < NN) dinv[g] = rsqrtf((float)(v + 1));  // +1 self-loop
        sh[t] = v; __syncthreads();
        for (int d = 1; d < 256; d <<= 1) {
            int x2 = (t >= d) ? sh[t - d] : 0; __syncthreads();
            sh[t] += x2; __syncthreads();
        }
        if (g < NN) off[g] = sh[t] - v;
        if (t == 255) bsum[blockIdx.x - gb] = sh[255];
    }
}

// ---------- K4: conv1-mgemm ∥ CSR fill ----------
__global__ __launch_bounds__(256) void k4_k(
    const unsigned short* __restrict__ bufB, const unsigned short* __restrict__ t2,
    const float* __restrict__ dinv, unsigned short* __restrict__ bufA,
    const int* __restrict__ src, const int* __restrict__ dst,
    const int* __restrict__ off, const int* __restrict__ bsum,
    int* __restrict__ cur, unsigned short* __restrict__ csr, int gb)
{
    if ((int)blockIdx.x < gb) {
        mgemm_dev<128, 128, 0, false, true, false, false>(blockIdx.x, bufB, t2, nullptr, dinv, bufA, NN);
    } else {
        int g = (blockIdx.x - gb) * 256 + threadIdx.x;
        if (g < NE) {
            int d = dst[g];
            int p = atomicAdd(&cur[d], 1);
            csr[off[d] + bsum[d >> 8] + p] = (unsigned short)src[g];
        }
    }
}

// ---------- GCN aggregation: out[d] = relu(dinv[d]*(hws[d] + sum_in hws[s]) + b) ----------
__global__ __launch_bounds__(256) void agg_k(
    const uint2* __restrict__ hws,  // [N][32] uint2
    const int* __restrict__ off, const int* __restrict__ bsum,
    const unsigned short* __restrict__ csr,
    const float* __restrict__ dinv, const float* __restrict__ bias,
    uint2* __restrict__ out, int n)
{
    int node = blockIdx.x * 8 + (threadIdx.x >> 5);
    if (node >= n) return;
    int lane = threadIdx.x & 31;

    uint2 v = hws[node * 32 + lane];  // self-loop term
    float s0 = bflo(v.x), s1 = bfhi(v.x), s2 = bflo(v.y), s3 = bfhi(v.y);

    int b = off[node] + bsum[node >> 8];
    int e = (node + 1 < n) ? (off[node + 1] + bsum[(node + 1) >> 8]) : NE;
    int j = b;
    for (; j + 8 <= e; j += 8) {
        uint2 t[8];
        #pragma unroll
        for (int u = 0; u < 8; u++) t[u] = hws[(int)csr[j + u] * 32 + lane];
        #pragma unroll
        for (int u = 0; u < 8; u++) {
            s0 += bflo(t[u].x); s1 += bfhi(t[u].x);
            s2 += bflo(t[u].y); s3 += bfhi(t[u].y);
        }
    }
    for (; j < e; j++) {
        uint2 t = hws[(int)csr[j] * 32 + lane];
        s0 += bflo(t.x); s1 += bfhi(t.x);
        s2 += bflo(t.y); s3 += bfhi(t.y);
    }

    float di = dinv[node];
    float4 bv = *(const float4*)(bias + 4 * lane);
    float r0 = fmaxf(fmaf(di, s0, bv.x), 0.f);
    float r1 = fmaxf(fmaf(di, s1, bv.y), 0.f);
    float r2 = fmaxf(fmaf(di, s2, bv.z), 0.f);
    float r3 = fmaxf(fmaf(di, s3, bv.w), 0.f);
    uint2 o; o.x = pack2(r0, r1); o.y = pack2(r2, r3);
    out[node * 32 + lane] = o;
}

// ---------- launch ----------
extern "C" void kernel_launch(void* const* d_in, const int* in_sizes, int n_in,
                              void* d_out, int out_size, void* d_ws, size_t ws_size,
                              hipStream_t stream)
{
    const float* x      = (const float*)d_in[0];
    const int*   ei     = (const int*)d_in[1];
    const float* enc_w1 = (const float*)d_in[2];
    const float* enc_b1 = (const float*)d_in[3];
    const float* enc_w2 = (const float*)d_in[4];
    const float* enc_b2 = (const float*)d_in[5];
    const float* w_c1   = (const float*)d_in[6];
    const float* b_c1   = (const float*)d_in[7];
    const float* w_c2   = (const float*)d_in[8];
    const float* b_c2   = (const float*)d_in[9];
    const float* w_c3   = (const float*)d_in[10];
    const float* b_c3   = (const float*)d_in[11];
    const float* dec_w1 = (const float*)d_in[12];
    const float* dec_b1 = (const float*)d_in[13];
    const float* dec_w2 = (const float*)d_in[14];
    const float* dec_b2 = (const float*)d_in[15];

    const int* src = ei;
    const int* dst = ei + NE;

    const int NP = 50048;  // rows padded to multiple of 64

    char* ws = (char*)d_ws;
    size_t o = 0;
    auto alloc = [&](size_t bytes) -> void* {
        void* p = ws + o;
        o = (o + bytes + 255) & ~(size_t)255;
        return p;
    };
    int*   cnt  = (int*)alloc((size_t)NN * 4);   // cnt and cur adjacent: one memset
    int*   cur  = (int*)alloc((size_t)NN * 4);
    int*   off  = (int*)alloc((size_t)(NN + 1) * 4);
    int*   bsum = (int*)alloc(256 * 4);
    unsigned short* csr = (unsigned short*)alloc((size_t)NE * 2);
    float* dinv = (float*)alloc((size_t)NN * 4);
    unsigned short* bufA = (unsigned short*)alloc((size_t)NP * HD * 2);
    unsigned short* bufB = (unsigned short*)alloc((size_t)NP * HD * 2);
    unsigned short* t0 = (unsigned short*)alloc(64 * 128 * 2);   // enc_w1^T (swizzled)
    unsigned short* t1 = (unsigned short*)alloc(128 * 128 * 2);  // enc_w2^T
    unsigned short* t2 = (unsigned short*)alloc(128 * 128 * 2);  // w_c1^T
    unsigned short* t3 = (unsigned short*)alloc(128 * 128 * 2);  // w_c2^T
    unsigned short* t4 = (unsigned short*)alloc(128 * 128 * 2);  // w_c3^T
    unsigned short* t5 = (unsigned short*)alloc(128 * 128 * 2);  // dec_w1^T
    unsigned short* t6 = (unsigned short*)alloc(128 * 64 * 2);   // dec_w2^T
    (void)ws_size; (void)n_in; (void)in_sizes; (void)out_size;

    // single memset covers cnt + cur (adjacent, 256-aligned)
    hipMemsetAsync(cnt, 0, (size_t)((char*)cur - (char*)cnt) + (size_t)NN * 4, stream);

    const int HB = (NE + 255) / 256;   // 3125 edge blocks
    const int NB_ = (NN + 255) / 256;  // 196 node blocks
    const int GB = NP / 64;            // 782 gemm row-tiles
    const int AB = (NN + 7) / 8;       // 6250 agg blocks

    // prep chain overlapped with encoder chain via block-range merged kernels
    wt_k<<<384, 256, 0, stream>>>(enc_w1, enc_w2, w_c1, w_c2, w_c3, dec_w1, dec_w2,
                                  t0, t1, t2, t3, t4, t5, t6);
    k1_k<<<GB + HB, 256, 0, stream>>>(x, t0, enc_b1, bufA, dst, cnt, GB);          // enc1 ∥ hist
    k2_k<<<GB + NB_, 256, 0, stream>>>(bufA, t1, enc_b2, bufB, cnt, off, bsum, dinv, GB); // enc2 ∥ scanA
    scanB_k<<<1, 256, 0, stream>>>(bsum, NB_);
    k4_k<<<GB + HB, 256, 0, stream>>>(bufB, t2, dinv, bufA, src, dst, off, bsum, cur, csr, GB); // conv1 ∥ fill

    // conv1 agg
    agg_k<<<AB, 256, 0, stream>>>((const uint2*)bufA, off, bsum, csr, dinv, b_c1, (uint2*)bufB, NN);
    // conv2
    mgemm_k<128, 128, 0, false, true, false, false><<<GB, 256, 0, stream>>>(bufB, t3, nullptr, dinv, bufA, NN);
    agg_k<<<AB, 256, 0, stream>>>((const uint2*)bufA, off, bsum, csr, dinv, b_c2, (uint2*)bufB, NN);
    // conv3
    mgemm_k<128, 128, 0, false, true, false, false><<<GB, 256, 0, stream>>>(bufB, t4, nullptr, dinv, bufA, NN);
    agg_k<<<AB, 256, 0, stream>>>((const uint2*)bufA, off, bsum, csr, dinv, b_c3, (uint2*)bufB, NN);
    // decoder
    mgemm_k<128, 128, 1, true, false, false, false><<<GB, 256, 0, stream>>>(bufB, t5, dec_b1, nullptr, bufA, NN);
    mgemm_k<128, 64, 2, true, false, false, true><<<GB, 256, 0, stream>>>(bufA, t6, dec_b2, nullptr, d_out, NN);
}